// Round 3
// baseline (84.251 us; speedup 1.0000x reference)
//
#include <hip/hip_runtime.h>
#include <hip/hip_bf16.h>
#include <math.h>

#define KCOMP 1024
#define DDIM  6
#define BPTS  16384

#define SPLIT 16             // K-chunks per point group (one per wave)
#define CPT   (KCOMP/SPLIT)  // 64 components per thread
#define PTS   64             // points per block (one per lane)
#define NCOEF 28             // 21 quad + 6 linear + 1 const

// ---------------------------------------------------------------------------
// Kernel 1: per-component precompute, LOG2 DOMAIN. In-place, low VGPR.
// v2(x) = log2(w_k N(x; mu_k, Sigma_k)) = sum_t cf[t] z[t] + cf[27]
//   cf[0..20]  = log2e * (-0.5*P_ii diag / -P_ij offdiag)   (z = x_i x_j, i<=j)
//   cf[21..26] = log2e * (P mu)_i                           (z = x_i)
//   cf[27]     = log2e * (log w - 0.5(D log2pi + logdet) - 0.5 mu^T P mu)
// P = Sigma^{-1}. Sigma >= 0.1 I => v2 bounded above (~2): fixed-scale exp2
// sums cannot overflow; underflow would need best comp < -87 nats (unreachable).
// 64-thread blocks + launch_bounds(64,1): full VGPR budget, no scratch spills.
// ---------------------------------------------------------------------------
__global__ __launch_bounds__(64, 1) void gmm_precompute(
        const float* __restrict__ means,
        const float* __restrict__ covs,
        const float* __restrict__ weights,
        float* __restrict__ coefs) {
    int k = blockIdx.x * 64 + threadIdx.x;
    if (k >= KCOMP) return;

    // A holds covs, then is overwritten by L (lower) in-place.
    float A[6][6];
    const float* C = covs + k * 36;
    #pragma unroll
    for (int i = 0; i < 6; i++)
        #pragma unroll
        for (int j = 0; j < 6; j++)
            A[i][j] = C[i * 6 + j];

    // In-place Cholesky: lower triangle of A becomes L.
    float logdet = 0.0f;
    #pragma unroll
    for (int j = 0; j < 6; j++) {
        float d = A[j][j];
        #pragma unroll
        for (int t = 0; t < 6; t++) if (t < j) d -= A[j][t] * A[j][t];
        float ljj = sqrtf(d);
        logdet += logf(ljj);
        A[j][j] = ljj;
        float inv = 1.0f / ljj;
        #pragma unroll
        for (int i = 0; i < 6; i++) {
            if (i > j) {
                float s = A[i][j];
                #pragma unroll
                for (int t = 0; t < 6; t++) if (t < j) s -= A[i][t] * A[j][t];
                A[i][j] = s * inv;
            }
        }
    }
    logdet *= 2.0f;

    // Li = L^{-1} (lower), stored in its own array; upper of A unused now.
    float Li[6][6];
    #pragma unroll
    for (int j = 0; j < 6; j++) {
        float invd = 1.0f / A[j][j];
        Li[j][j] = invd;
        #pragma unroll
        for (int i = 0; i < 6; i++) {
            if (i > j) {
                float s = 0.0f;
                #pragma unroll
                for (int t = 0; t < 6; t++) if (t >= j && t < i) s += A[i][t] * Li[t][j];
                Li[i][j] = -s * (1.0f / A[i][i]);
            }
        }
    }

    // P = Li^T Li (symmetric) -> overwrite A.
    #pragma unroll
    for (int i = 0; i < 6; i++) {
        #pragma unroll
        for (int j = 0; j < 6; j++) {
            if (j >= i) {
                float s = 0.0f;
                int lo = (i > j) ? i : j;
                #pragma unroll
                for (int t = 0; t < 6; t++) if (t >= lo) s += Li[t][i] * Li[t][j];
                A[i][j] = s;
                A[j][i] = s;
            }
        }
    }

    const float* mu = means + k * 6;
    float m[6];
    #pragma unroll
    for (int i = 0; i < 6; i++) m[i] = mu[i];

    float b[6];
    float muPmu = 0.0f;
    #pragma unroll
    for (int i = 0; i < 6; i++) {
        float s = 0.0f;
        #pragma unroll
        for (int j = 0; j < 6; j++) s += A[i][j] * m[j];
        b[i] = s;
        muPmu += s * m[i];
    }

    const float LOG_2PI = 1.8378770664093453f;
    const float LOG2E   = 1.4426950408889634f;
    float c = logf(weights[k]) - 0.5f * (6.0f * LOG_2PI + logdet) - 0.5f * muPmu;

    float* cf = coefs + k * NCOEF;
    int t = 0;
    #pragma unroll
    for (int i = 0; i < 6; i++)
        #pragma unroll
        for (int j = 0; j < 6; j++)
            if (j >= i) cf[t++] = LOG2E * ((i == j) ? -0.5f * A[i][j] : -A[i][j]);
    #pragma unroll
    for (int i = 0; i < 6; i++) cf[t++] = LOG2E * b[i];
    cf[27] = LOG2E * c;
}

// ---------------------------------------------------------------------------
// Kernel 2: main. 256 blocks x 1024 threads (16 waves, 4 waves/SIMD). Wave w
// = K-chunk w (wave-uniform address -> s_load for coefs). Lane l = point
// blockIdx.x*64+l. Software-pipelined coef prefetch (distance 1) so SMEM
// latency (~200 cyc) is covered by ~60 cyc lead x 4 resident waves.
// ---------------------------------------------------------------------------
struct C7 { float4 v[7]; };   // one component's 28 coefs

__device__ __forceinline__ C7 ld7(const float4* __restrict__ p) {
    C7 c;
    #pragma unroll
    for (int i = 0; i < 7; i++) c.v[i] = p[i];
    return c;
}

__device__ __forceinline__ float dot27(const C7& c, const float* __restrict__ z) {
    float cfa[28];
    #pragma unroll
    for (int i = 0; i < 7; i++) {
        cfa[4 * i + 0] = c.v[i].x;
        cfa[4 * i + 1] = c.v[i].y;
        cfa[4 * i + 2] = c.v[i].z;
        cfa[4 * i + 3] = c.v[i].w;
    }
    float v0 = cfa[27], v1 = 0.0f, v2 = 0.0f;
    #pragma unroll
    for (int t = 0; t < 9; t++)  v0 = fmaf(cfa[t],      z[t],      v0);
    #pragma unroll
    for (int t = 0; t < 9; t++)  v1 = fmaf(cfa[t + 9],  z[t + 9],  v1);
    #pragma unroll
    for (int t = 0; t < 9; t++)  v2 = fmaf(cfa[t + 18], z[t + 18], v2);
    return (v0 + v1) + v2;
}

__global__ __launch_bounds__(1024, 4) void gmm_main(const float* __restrict__ x,
                                                    const float* __restrict__ coefs,
                                                    float* __restrict__ out) {
    const int lane = threadIdx.x & 63;
    const int wave = __builtin_amdgcn_readfirstlane((int)(threadIdx.x >> 6)); // 0..15
    const int p = blockIdx.x * PTS + lane;

    float xv[6];
    const float* xp = x + p * 6;
    #pragma unroll
    for (int i = 0; i < 6; i++) xv[i] = xp[i];

    float z[27];
    {
        int t = 0;
        #pragma unroll
        for (int i = 0; i < 6; i++)
            #pragma unroll
            for (int j = 0; j < 6; j++)
                if (j >= i) z[t++] = xv[i] * xv[j];
        #pragma unroll
        for (int i = 0; i < 6; i++) z[t++] = xv[i];
    }

    const float4* cf4 = (const float4*)(coefs + (size_t)wave * CPT * NCOEF);

    float s0 = 0.0f, s1 = 0.0f;
    C7 cur = ld7(cf4);

    #pragma unroll 2
    for (int j = 0; j < CPT - 1; j++) {
        C7 nxt = ld7(cf4 + (j + 1) * 7);       // prefetch next component's coefs
        float e = __builtin_amdgcn_exp2f(dot27(cur, z));
        if (j & 1) s1 += e; else s0 += e;
        cur = nxt;
    }
    s0 += __builtin_amdgcn_exp2f(dot27(cur, z));

    __shared__ float ss[SPLIT][PTS];
    ss[wave][lane] = s0 + s1;
    __syncthreads();

    if (threadIdx.x < PTS) {
        float S = 0.0f;
        #pragma unroll
        for (int c = 0; c < SPLIT; c++) S += ss[c][lane];
        const float LN2 = 0.6931471805599453f;
        out[p] = LN2 * __builtin_amdgcn_logf(S);  // v_log_f32 = log2
    }
}

extern "C" void kernel_launch(void* const* d_in, const int* in_sizes, int n_in,
                              void* d_out, int out_size, void* d_ws, size_t ws_size,
                              hipStream_t stream) {
    const float* x       = (const float*)d_in[0];  // [B, 6]
    const float* means   = (const float*)d_in[1];  // [K, 6]
    const float* covs    = (const float*)d_in[2];  // [K, 6, 6]
    const float* weights = (const float*)d_in[3];  // [K]
    float* out = (float*)d_out;                    // [B]
    float* coefs = (float*)d_ws;                   // [K, 28] = 114,688 B

    gmm_precompute<<<KCOMP / 64, 64, 0, stream>>>(means, covs, weights, coefs);
    gmm_main<<<BPTS / PTS, 1024, 0, stream>>>(x, coefs, out);
}

// Round 4
// 68.701 us; speedup vs baseline: 1.2263x; 1.2263x over previous
//
#include <hip/hip_runtime.h>
#include <hip/hip_bf16.h>
#include <math.h>

#define KCOMP 1024
#define DDIM  6
#define BPTS  16384

#define PTS    64            // points per block (4 MFMA pt-tiles of 16)
#define NWAVE  16            // waves per block; wave w owns comps [w*64, w*64+64)
#define NTPW   4             // n-tiles per wave (4 x 16 = 64 comps)

typedef __attribute__((ext_vector_type(8))) short bf16x8;  // 8 bf16 = 4 VGPRs
typedef __attribute__((ext_vector_type(4))) float f32x4;

// self-contained bf16 helpers (RNE), no dependence on __hip_bfloat16 ABI
__device__ __forceinline__ unsigned short f32_to_bf16(float f) {
    unsigned int u = __float_as_uint(f);
    u += 0x7fffu + ((u >> 16) & 1u);
    return (unsigned short)(u >> 16);
}
__device__ __forceinline__ float bf16_to_f32(unsigned short h) {
    return __uint_as_float(((unsigned int)h) << 16);
}

// ---------------------------------------------------------------------------
// Kernel 1: per-component precompute -> split-bf16 W matrix in MFMA B-operand
// fragment order.
// Log2-domain score: v2[b,k] = sum_{t<32} Z[b,t] * W[t,k]
//   W[0..20,k]  = log2e * (-0.5*P_ii diag / -P_ij offdiag)   (Z: x_i x_j, i<=j)
//   W[21..26,k] = log2e * (P mu)_i                            (Z: x_i)
//   W[27,k]     = log2e * (log w - 0.5(D log2pi + logdet) - 0.5 mu^T P mu)  (Z: 1)
//   W[28..31,k] = 0                                           (Z: 0 pad)
// P = Sigma^{-1}. Sigma >= 0.1 I => v2 bounded above (~2): fixed-scale exp2
// sums cannot overflow; all-comp underflow needs best < -87 nats (unreachable).
// Split: W = Whi + Wlo (two bf16 -> ~16-bit mantissa).
// Fragment order (16x16x32 B-operand: lane=(kq<<4)|n15 holds B[kq*8+j][n]):
//   idx(n,k) = ((n>>4)*64 + ((k>>3)<<4) + (n&15))*8 + (k&7)
// ---------------------------------------------------------------------------
__global__ __launch_bounds__(64, 1) void gmm_precompute(
        const float* __restrict__ means,
        const float* __restrict__ covs,
        const float* __restrict__ weights,
        unsigned short* __restrict__ Wh,     // [32768]
        unsigned short* __restrict__ Wl) {   // [32768]
    int k = blockIdx.x * 64 + threadIdx.x;
    if (k >= KCOMP) return;

    float A[6][6];
    const float* C = covs + k * 36;
    #pragma unroll
    for (int i = 0; i < 6; i++)
        #pragma unroll
        for (int j = 0; j < 6; j++)
            A[i][j] = C[i * 6 + j];

    // In-place Cholesky: lower triangle of A becomes L.
    float logdet = 0.0f;
    #pragma unroll
    for (int j = 0; j < 6; j++) {
        float d = A[j][j];
        #pragma unroll
        for (int t = 0; t < 6; t++) if (t < j) d -= A[j][t] * A[j][t];
        float ljj = sqrtf(d);
        logdet += logf(ljj);
        A[j][j] = ljj;
        float inv = 1.0f / ljj;
        #pragma unroll
        for (int i = 0; i < 6; i++) {
            if (i > j) {
                float s = A[i][j];
                #pragma unroll
                for (int t = 0; t < 6; t++) if (t < j) s -= A[i][t] * A[j][t];
                A[i][j] = s * inv;
            }
        }
    }
    logdet *= 2.0f;

    // Li = L^{-1} (lower)
    float Li[6][6];
    #pragma unroll
    for (int j = 0; j < 6; j++) {
        Li[j][j] = 1.0f / A[j][j];
        #pragma unroll
        for (int i = 0; i < 6; i++) {
            if (i > j) {
                float s = 0.0f;
                #pragma unroll
                for (int t = 0; t < 6; t++) if (t >= j && t < i) s += A[i][t] * Li[t][j];
                Li[i][j] = -s * (1.0f / A[i][i]);
            }
        }
    }

    // P = Li^T Li -> overwrite A
    #pragma unroll
    for (int i = 0; i < 6; i++) {
        #pragma unroll
        for (int j = 0; j < 6; j++) {
            if (j >= i) {
                float s = 0.0f;
                int lo = (i > j) ? i : j;
                #pragma unroll
                for (int t = 0; t < 6; t++) if (t >= lo) s += Li[t][i] * Li[t][j];
                A[i][j] = s;
                A[j][i] = s;
            }
        }
    }

    const float* mu = means + k * 6;
    float m[6];
    #pragma unroll
    for (int i = 0; i < 6; i++) m[i] = mu[i];

    float b[6];
    float muPmu = 0.0f;
    #pragma unroll
    for (int i = 0; i < 6; i++) {
        float s = 0.0f;
        #pragma unroll
        for (int j = 0; j < 6; j++) s += A[i][j] * m[j];
        b[i] = s;
        muPmu += s * m[i];
    }

    const float LOG_2PI = 1.8378770664093453f;
    const float LOG2E   = 1.4426950408889634f;
    float c = logf(weights[k]) - 0.5f * (6.0f * LOG_2PI + logdet) - 0.5f * muPmu;

    float wv[32];
    int t = 0;
    #pragma unroll
    for (int i = 0; i < 6; i++)
        #pragma unroll
        for (int j = 0; j < 6; j++)
            if (j >= i) wv[t++] = LOG2E * ((i == j) ? -0.5f * A[i][j] : -A[i][j]);
    #pragma unroll
    for (int i = 0; i < 6; i++) wv[t++] = LOG2E * b[i];
    wv[27] = LOG2E * c;
    wv[28] = 0.0f; wv[29] = 0.0f; wv[30] = 0.0f; wv[31] = 0.0f;

    int ntile = k >> 4, n15 = k & 15;
    #pragma unroll
    for (int kk = 0; kk < 32; kk++) {
        float v = wv[kk];
        unsigned short h = f32_to_bf16(v);
        unsigned short l = f32_to_bf16(v - bf16_to_f32(h));
        int idx = ((ntile * 64) + ((kk >> 3) << 4) + n15) * 8 + (kk & 7);
        Wh[idx] = h;
        Wl[idx] = l;
    }
}

// ---------------------------------------------------------------------------
// Kernel 2: MFMA main. 256 blocks x 1024 threads (16 waves, 4 waves/SIMD).
// Block: 64 points (4 pt-tiles). Wave w: comps [w*64, w*64+64) (4 n-tiles).
// Per (pt,n) tile: 3x mfma_f32_16x16x32_bf16 (split-bf16 fp32-ish precision),
// then exp2 on the 4 C-regs, accumulate; cross-lane xor-reduce over the 16
// comp-lanes, LDS combine over the 16 waves.
// A-operand layout: lane=(quad<<4)|m holds Z[m][quad*8+j].
// C/D layout: col(comp)=lane&15, row(point)=quad*4+reg.
// ---------------------------------------------------------------------------
__global__ __launch_bounds__(1024, 4) void gmm_main(
        const float* __restrict__ x,
        const unsigned short* __restrict__ Wh,
        const unsigned short* __restrict__ Wl,
        float* __restrict__ out) {
    const int tid  = threadIdx.x;
    const int lane = tid & 63;
    const int w    = __builtin_amdgcn_readfirstlane(tid >> 6);  // 0..15
    const int quad = lane >> 4;                                  // 0..3
    const int m15  = lane & 15;
    const int pbase = blockIdx.x * PTS;

    // ---- load x for this lane's 4 points (one per pt-tile) ----
    float xv[4][6];
    #pragma unroll
    for (int pt = 0; pt < 4; pt++) {
        const float* xp = x + (pbase + pt * 16 + m15) * 6;
        #pragma unroll
        for (int i = 0; i < 6; i++) xv[pt][i] = xp[i];
    }

    // ---- build A fragments (features quad*8..quad*8+7 for each pt-tile) ----
    float f[4][8];
    if (quad == 0) {
        #pragma unroll
        for (int pt = 0; pt < 4; pt++) {
            const float* v = xv[pt];
            f[pt][0]=v[0]*v[0]; f[pt][1]=v[0]*v[1]; f[pt][2]=v[0]*v[2]; f[pt][3]=v[0]*v[3];
            f[pt][4]=v[0]*v[4]; f[pt][5]=v[0]*v[5]; f[pt][6]=v[1]*v[1]; f[pt][7]=v[1]*v[2];
        }
    } else if (quad == 1) {
        #pragma unroll
        for (int pt = 0; pt < 4; pt++) {
            const float* v = xv[pt];
            f[pt][0]=v[1]*v[3]; f[pt][1]=v[1]*v[4]; f[pt][2]=v[1]*v[5]; f[pt][3]=v[2]*v[2];
            f[pt][4]=v[2]*v[3]; f[pt][5]=v[2]*v[4]; f[pt][6]=v[2]*v[5]; f[pt][7]=v[3]*v[3];
        }
    } else if (quad == 2) {
        #pragma unroll
        for (int pt = 0; pt < 4; pt++) {
            const float* v = xv[pt];
            f[pt][0]=v[3]*v[4]; f[pt][1]=v[3]*v[5]; f[pt][2]=v[4]*v[4]; f[pt][3]=v[4]*v[5];
            f[pt][4]=v[5]*v[5]; f[pt][5]=v[0];      f[pt][6]=v[1];      f[pt][7]=v[2];
        }
    } else {
        #pragma unroll
        for (int pt = 0; pt < 4; pt++) {
            const float* v = xv[pt];
            f[pt][0]=v[3]; f[pt][1]=v[4]; f[pt][2]=v[5]; f[pt][3]=1.0f;
            f[pt][4]=0.0f; f[pt][5]=0.0f; f[pt][6]=0.0f; f[pt][7]=0.0f;
        }
    }

    bf16x8 Ah[4], Al[4];
    #pragma unroll
    for (int pt = 0; pt < 4; pt++) {
        #pragma unroll
        for (int j = 0; j < 8; j++) {
            float v = f[pt][j];
            unsigned short h = f32_to_bf16(v);
            unsigned short l = f32_to_bf16(v - bf16_to_f32(h));
            Ah[pt][j] = (short)h;
            Al[pt][j] = (short)l;
        }
    }

    // ---- MFMA loop over this wave's 4 n-tiles ----
    const bf16x8* WhF = (const bf16x8*)Wh + (w * NTPW) * 64;
    const bf16x8* WlF = (const bf16x8*)Wl + (w * NTPW) * 64;

    float esum[4][4];
    #pragma unroll
    for (int pt = 0; pt < 4; pt++)
        #pragma unroll
        for (int r = 0; r < 4; r++) esum[pt][r] = 0.0f;

    #pragma unroll
    for (int t = 0; t < NTPW; t++) {
        bf16x8 bh = WhF[t * 64 + lane];
        bf16x8 bl = WlF[t * 64 + lane];
        #pragma unroll
        for (int pt = 0; pt < 4; pt++) {
            f32x4 c = {0.0f, 0.0f, 0.0f, 0.0f};
            c = __builtin_amdgcn_mfma_f32_16x16x32_bf16(Ah[pt], bh, c, 0, 0, 0);
            c = __builtin_amdgcn_mfma_f32_16x16x32_bf16(Al[pt], bh, c, 0, 0, 0);
            c = __builtin_amdgcn_mfma_f32_16x16x32_bf16(Ah[pt], bl, c, 0, 0, 0);
            #pragma unroll
            for (int r = 0; r < 4; r++)
                esum[pt][r] += __builtin_amdgcn_exp2f(c[r]);
        }
    }

    // ---- reduce over the 16 comp-lanes (xor butterfly within 16-group) ----
    #pragma unroll
    for (int pt = 0; pt < 4; pt++) {
        #pragma unroll
        for (int r = 0; r < 4; r++) {
            float v = esum[pt][r];
            v += __shfl_xor(v, 1);
            v += __shfl_xor(v, 2);
            v += __shfl_xor(v, 4);
            v += __shfl_xor(v, 8);
            esum[pt][r] = v;
        }
    }

    __shared__ float partial[NWAVE][PTS];
    if (m15 == 0) {
        #pragma unroll
        for (int pt = 0; pt < 4; pt++)
            #pragma unroll
            for (int r = 0; r < 4; r++)
                partial[w][pt * 16 + quad * 4 + r] = esum[pt][r];
    }
    __syncthreads();

    if (tid < PTS) {
        float S = 0.0f;
        #pragma unroll
        for (int c = 0; c < NWAVE; c++) S += partial[c][tid];
        const float LN2 = 0.6931471805599453f;
        out[pbase + tid] = LN2 * __builtin_amdgcn_logf(S);  // v_log_f32 = log2
    }
}

extern "C" void kernel_launch(void* const* d_in, const int* in_sizes, int n_in,
                              void* d_out, int out_size, void* d_ws, size_t ws_size,
                              hipStream_t stream) {
    const float* x       = (const float*)d_in[0];  // [B, 6]
    const float* means   = (const float*)d_in[1];  // [K, 6]
    const float* covs    = (const float*)d_in[2];  // [K, 6, 6]
    const float* weights = (const float*)d_in[3];  // [K]
    float* out = (float*)d_out;                    // [B]

    unsigned short* Wh = (unsigned short*)d_ws;            // 32768 x bf16 (64 KB)
    unsigned short* Wl = Wh + 32768;                       // 32768 x bf16 (64 KB)

    gmm_precompute<<<KCOMP / 64, 64, 0, stream>>>(means, covs, weights, Wh, Wl);
    gmm_main<<<BPTS / PTS, 1024, 0, stream>>>(x, Wh, Wl, out);
}

// Round 5
// 66.961 us; speedup vs baseline: 1.2582x; 1.0260x over previous
//
#include <hip/hip_runtime.h>
#include <hip/hip_bf16.h>
#include <math.h>

#define KCOMP 1024
#define DDIM  6
#define BPTS  16384

#define PTS    64            // points per block (4 MFMA pt-tiles of 16)
#define NWAVE  16            // waves per block; wave w owns comps [w*64, w*64+64)
#define NTPW   4             // n-tiles per wave (4 x 16 = 64 comps)

typedef __attribute__((ext_vector_type(8))) short bf16x8;  // 8 bf16 = 4 VGPRs
typedef __attribute__((ext_vector_type(4))) float f32x4;

// self-contained bf16 helpers (RNE)
__device__ __forceinline__ unsigned short f32_to_bf16(float f) {
    unsigned int u = __float_as_uint(f);
    u += 0x7fffu + ((u >> 16) & 1u);
    return (unsigned short)(u >> 16);
}
__device__ __forceinline__ float bf16_to_f32(unsigned short h) {
    return __uint_as_float(((unsigned int)h) << 16);
}

// ---------------------------------------------------------------------------
// Kernel 1: per-component precompute -> split-bf16 W matrix in MFMA B-operand
// fragment order. LOG2 domain throughout.
//   W[0..20,k]  = log2e * (-0.5*P_ii diag / -P_ij offdiag)   (Z: x_i x_j, i<=j)
//   W[21..26,k] = log2e * (P mu)_i                            (Z: x_i)
//   W[27,k]     = log2(w) - 0.5*(6*log2(2pi) + logdet2) - 0.5*log2e*mu^T P mu
//   W[28..31,k] = 0
// P = Sigma^{-1}. Sigma >= 0.1 I => v2 bounded above (~2): fixed-scale exp2
// sums cannot overflow; all-comp underflow needs best < -87 nats (unreachable).
// Fast-math: v_sqrt/v_rcp/v_log (1-ulp) — error far below the bf16-split term.
// logdet2 = 2*log2(prod diag(L)) — ONE v_log_f32 instead of 6 libm logf.
// Fragment order (16x16x32 B-operand: lane=(kq<<4)|n15 holds B[kq*8+j][n]):
//   idx(n,k) = ((n>>4)*64 + ((k>>3)<<4) + (n&15))*8 + (k&7)
// ---------------------------------------------------------------------------
__global__ __launch_bounds__(64, 1) void gmm_precompute(
        const float* __restrict__ means,
        const float* __restrict__ covs,
        const float* __restrict__ weights,
        unsigned short* __restrict__ Wh,     // [32768]
        unsigned short* __restrict__ Wl) {   // [32768]
    int k = blockIdx.x * 64 + threadIdx.x;
    if (k >= KCOMP) return;

    float A[6][6];
    const float* C = covs + k * 36;
    #pragma unroll
    for (int i = 0; i < 6; i++)
        #pragma unroll
        for (int j = 0; j < 6; j++)
            A[i][j] = C[i * 6 + j];

    // In-place Cholesky: lower triangle of A becomes L. Track diag product.
    float dprod = 1.0f;
    #pragma unroll
    for (int j = 0; j < 6; j++) {
        float d = A[j][j];
        #pragma unroll
        for (int t = 0; t < 6; t++) if (t < j) d -= A[j][t] * A[j][t];
        float ljj = __builtin_amdgcn_sqrtf(d);
        dprod *= ljj;
        A[j][j] = ljj;
        float inv = __builtin_amdgcn_rcpf(ljj);
        #pragma unroll
        for (int i = 0; i < 6; i++) {
            if (i > j) {
                float s = A[i][j];
                #pragma unroll
                for (int t = 0; t < 6; t++) if (t < j) s -= A[i][t] * A[j][t];
                A[i][j] = s * inv;
            }
        }
    }
    float logdet2 = 2.0f * __builtin_amdgcn_logf(dprod);   // log2(det Sigma)

    // Li = L^{-1} (lower)
    float Li[6][6];
    #pragma unroll
    for (int j = 0; j < 6; j++) {
        Li[j][j] = __builtin_amdgcn_rcpf(A[j][j]);
        #pragma unroll
        for (int i = 0; i < 6; i++) {
            if (i > j) {
                float s = 0.0f;
                #pragma unroll
                for (int t = 0; t < 6; t++) if (t >= j && t < i) s += A[i][t] * Li[t][j];
                Li[i][j] = -s * __builtin_amdgcn_rcpf(A[i][i]);
            }
        }
    }

    // P = Li^T Li -> overwrite A
    #pragma unroll
    for (int i = 0; i < 6; i++) {
        #pragma unroll
        for (int j = 0; j < 6; j++) {
            if (j >= i) {
                float s = 0.0f;
                int lo = (i > j) ? i : j;
                #pragma unroll
                for (int t = 0; t < 6; t++) if (t >= lo) s += Li[t][i] * Li[t][j];
                A[i][j] = s;
                A[j][i] = s;
            }
        }
    }

    const float* mu = means + k * 6;
    float m[6];
    #pragma unroll
    for (int i = 0; i < 6; i++) m[i] = mu[i];

    float b[6];
    float muPmu = 0.0f;
    #pragma unroll
    for (int i = 0; i < 6; i++) {
        float s = 0.0f;
        #pragma unroll
        for (int j = 0; j < 6; j++) s += A[i][j] * m[j];
        b[i] = s;
        muPmu += s * m[i];
    }

    const float LOG2_2PI = 2.6514961294723187f;   // log2(2*pi)
    const float LOG2E    = 1.4426950408889634f;
    float c2 = __builtin_amdgcn_logf(weights[k])
             - 0.5f * (6.0f * LOG2_2PI + logdet2)
             - 0.5f * LOG2E * muPmu;

    float wv[32];
    int t = 0;
    #pragma unroll
    for (int i = 0; i < 6; i++)
        #pragma unroll
        for (int j = 0; j < 6; j++)
            if (j >= i) wv[t++] = LOG2E * ((i == j) ? -0.5f * A[i][j] : -A[i][j]);
    #pragma unroll
    for (int i = 0; i < 6; i++) wv[t++] = LOG2E * b[i];
    wv[27] = c2;
    wv[28] = 0.0f; wv[29] = 0.0f; wv[30] = 0.0f; wv[31] = 0.0f;

    int ntile = k >> 4, n15 = k & 15;
    #pragma unroll
    for (int kk = 0; kk < 32; kk++) {
        float v = wv[kk];
        unsigned short h = f32_to_bf16(v);
        unsigned short l = f32_to_bf16(v - bf16_to_f32(h));
        int idx = ((ntile * 64) + ((kk >> 3) << 4) + n15) * 8 + (kk & 7);
        Wh[idx] = h;
        Wl[idx] = l;
    }
}

// ---------------------------------------------------------------------------
// Kernel 2: MFMA main. 256 blocks x 1024 threads (16 waves, 4 waves/SIMD).
// Block: 64 points (4 pt-tiles). Wave w: comps [w*64, w*64+64) (4 n-tiles).
// A-fragment build is de-duplicated: 8 producer waves (job = split*4 + pt)
// each build ONE pt-tile x {hi,lo} fragment set into LDS; all 16 waves
// ds_read_b128 them back (was: every wave rebuilt all 8 — ~700 cyc/wave waste).
// Per (pt,n) tile: 3x mfma_f32_16x16x32_bf16 (split-bf16), exp2 on 4 C-regs,
// accumulate; xor-reduce over 16 comp-lanes; LDS combine over 16 waves.
// A-operand layout: lane=(quad<<4)|m holds Z[m][quad*8+j].
// C/D layout: col(comp)=lane&15, row(point)=quad*4+reg.
// ---------------------------------------------------------------------------
__global__ __launch_bounds__(1024, 4) void gmm_main(
        const float* __restrict__ x,
        const unsigned short* __restrict__ Wh,
        const unsigned short* __restrict__ Wl,
        float* __restrict__ out) {
    const int tid  = threadIdx.x;
    const int lane = tid & 63;
    const int w    = __builtin_amdgcn_readfirstlane(tid >> 6);  // 0..15
    const int quad = lane >> 4;                                  // 0..3
    const int m15  = lane & 15;
    const int pbase = blockIdx.x * PTS;

    __shared__ bf16x8 fragA[8][64];          // [split*4+pt][lane], 8 KB
    __shared__ float  partial[NWAVE][PTS];   // 4 KB

    // ---- producer waves: build one (pt, split) fragment set ----
    if (w < 8) {
        const int pt    = w & 3;
        const int split = w >> 2;            // 0 = hi, 1 = lo
        float v[6];
        const float* xp = x + (pbase + pt * 16 + m15) * 6;
        #pragma unroll
        for (int i = 0; i < 6; i++) v[i] = xp[i];

        float f[8];
        if (quad == 0) {
            f[0]=v[0]*v[0]; f[1]=v[0]*v[1]; f[2]=v[0]*v[2]; f[3]=v[0]*v[3];
            f[4]=v[0]*v[4]; f[5]=v[0]*v[5]; f[6]=v[1]*v[1]; f[7]=v[1]*v[2];
        } else if (quad == 1) {
            f[0]=v[1]*v[3]; f[1]=v[1]*v[4]; f[2]=v[1]*v[5]; f[3]=v[2]*v[2];
            f[4]=v[2]*v[3]; f[5]=v[2]*v[4]; f[6]=v[2]*v[5]; f[7]=v[3]*v[3];
        } else if (quad == 2) {
            f[0]=v[3]*v[4]; f[1]=v[3]*v[5]; f[2]=v[4]*v[4]; f[3]=v[4]*v[5];
            f[4]=v[5]*v[5]; f[5]=v[0];      f[6]=v[1];      f[7]=v[2];
        } else {
            f[0]=v[3]; f[1]=v[4]; f[2]=v[5]; f[3]=1.0f;
            f[4]=0.0f; f[5]=0.0f; f[6]=0.0f; f[7]=0.0f;
        }

        bf16x8 frag;
        #pragma unroll
        for (int j = 0; j < 8; j++) {
            unsigned short h = f32_to_bf16(f[j]);
            frag[j] = (split == 0) ? (short)h
                                   : (short)f32_to_bf16(f[j] - bf16_to_f32(h));
        }
        fragA[w][lane] = frag;
    }
    __syncthreads();

    bf16x8 Ah[4], Al[4];
    #pragma unroll
    for (int pt = 0; pt < 4; pt++) {
        Ah[pt] = fragA[pt][lane];
        Al[pt] = fragA[4 + pt][lane];
    }

    // ---- MFMA loop over this wave's 4 n-tiles ----
    const bf16x8* WhF = (const bf16x8*)Wh + (w * NTPW) * 64;
    const bf16x8* WlF = (const bf16x8*)Wl + (w * NTPW) * 64;

    float esum[4][4];
    #pragma unroll
    for (int pt = 0; pt < 4; pt++)
        #pragma unroll
        for (int r = 0; r < 4; r++) esum[pt][r] = 0.0f;

    #pragma unroll
    for (int t = 0; t < NTPW; t++) {
        bf16x8 bh = WhF[t * 64 + lane];
        bf16x8 bl = WlF[t * 64 + lane];
        #pragma unroll
        for (int pt = 0; pt < 4; pt++) {
            f32x4 c = {0.0f, 0.0f, 0.0f, 0.0f};
            c = __builtin_amdgcn_mfma_f32_16x16x32_bf16(Ah[pt], bh, c, 0, 0, 0);
            c = __builtin_amdgcn_mfma_f32_16x16x32_bf16(Al[pt], bh, c, 0, 0, 0);
            c = __builtin_amdgcn_mfma_f32_16x16x32_bf16(Ah[pt], bl, c, 0, 0, 0);
            #pragma unroll
            for (int r = 0; r < 4; r++)
                esum[pt][r] += __builtin_amdgcn_exp2f(c[r]);
        }
    }

    // ---- reduce over the 16 comp-lanes (xor butterfly within 16-group) ----
    #pragma unroll
    for (int pt = 0; pt < 4; pt++) {
        #pragma unroll
        for (int r = 0; r < 4; r++) {
            float v = esum[pt][r];
            v += __shfl_xor(v, 1);
            v += __shfl_xor(v, 2);
            v += __shfl_xor(v, 4);
            v += __shfl_xor(v, 8);
            esum[pt][r] = v;
        }
    }

    if (m15 == 0) {
        #pragma unroll
        for (int pt = 0; pt < 4; pt++)
            #pragma unroll
            for (int r = 0; r < 4; r++)
                partial[w][pt * 16 + quad * 4 + r] = esum[pt][r];
    }
    __syncthreads();

    if (tid < PTS) {
        float S = 0.0f;
        #pragma unroll
        for (int c = 0; c < NWAVE; c++) S += partial[c][tid];
        const float LN2 = 0.6931471805599453f;
        out[pbase + tid] = LN2 * __builtin_amdgcn_logf(S);  // v_log_f32 = log2
    }
}

extern "C" void kernel_launch(void* const* d_in, const int* in_sizes, int n_in,
                              void* d_out, int out_size, void* d_ws, size_t ws_size,
                              hipStream_t stream) {
    const float* x       = (const float*)d_in[0];  // [B, 6]
    const float* means   = (const float*)d_in[1];  // [K, 6]
    const float* covs    = (const float*)d_in[2];  // [K, 6, 6]
    const float* weights = (const float*)d_in[3];  // [K]
    float* out = (float*)d_out;                    // [B]

    unsigned short* Wh = (unsigned short*)d_ws;            // 32768 x bf16 (64 KB)
    unsigned short* Wl = Wh + 32768;                       // 32768 x bf16 (64 KB)

    gmm_precompute<<<KCOMP / 64, 64, 0, stream>>>(means, covs, weights, Wh, Wl);
    gmm_main<<<BPTS / PTS, 1024, 0, stream>>>(x, Wh, Wl, out);
}